// Round 7
// baseline (459.190 us; speedup 1.0000x reference)
//
#include <hip/hip_runtime.h>

// B=16, T=1280000, C=4, up=5, down=64, K=1345, n_pre_remove=11, n_out=100000
// Identity (verified r1-r6): out[b,5q+r,c] = sum_{k=0}^{320} tab[k][r] * x[b, 64q+192-k, c]
//   tab[k][r] = h[5k-256+64r] (0 outside [0,1345)); taps padded to 352 (8 splits x 44)
// r7: persistent blocks + cross-tile pipeline (prefetch next tile's HBM reads into
// registers during current tile's compute); f16 plane LDS + dot2 preserved from r6.
typedef _Float16 h2 __attribute__((ext_vector_type(2)));
typedef _Float16 h4 __attribute__((ext_vector_type(4)));

#define T_IN   1280000
#define N_OUT  100000
#define NQ     20000
#define KH     1345
#define NMP    176        // f16 tap pairs per phase r (352/2)
#define NTILE  313        // tiles per batch (QT=64)
#define NTASK  5008       // NTILE * 16 batches
#define GRID   512        // persistent blocks, 2/CU
#define OFFJ   159        // jlo = 64*q0 - 159; sample i = 64*dq + 351 - k
#define NPAIR  2240       // staged sample pairs per tile
#define PLANE  9216       // bytes per f16 channel plane
#define SLOT   40960      // LDS slot: planes (36864) + reduce headroom
#define LDSSZ  81920      // two slots (double buffer)
#define SWZ(b) ((b) ^ ((((b) >> 7) & 15) << 3))
#define PKRTZ(a, b) __builtin_bit_cast(h2, __builtin_amdgcn_cvt_pkrtz((a), (b)))

// ws: u32-packed half2 tap pairs, ws[m*5+r] (verified r6)
__global__ void build_tables(const float* __restrict__ h, unsigned* __restrict__ ws) {
    int m = blockIdx.x * blockDim.x + threadIdx.x;
    if (m >= NMP) return;
    #pragma unroll
    for (int r = 0; r < 5; ++r) {
        int ilo = 5 * (2 * m)     - 256 + 64 * r;
        int ihi = 5 * (2 * m + 1) - 256 + 64 * r;
        float vlo = (ilo >= 0 && ilo < KH) ? h[ilo] : 0.f;
        float vhi = (ihi >= 0 && ihi < KH) ? h[ihi] : 0.f;
        h2 p = PKRTZ(vhi, vlo);
        ws[m * 5 + r] = __builtin_bit_cast(unsigned, p);
    }
}

#define DOT_R(AR, TH, TL) \
  AR.x = __builtin_amdgcn_fdot2(TH, Xl0, AR.x, false); \
  AR.x = __builtin_amdgcn_fdot2(TL, Xh0, AR.x, false); \
  AR.y = __builtin_amdgcn_fdot2(TH, Xl1, AR.y, false); \
  AR.y = __builtin_amdgcn_fdot2(TL, Xh1, AR.y, false); \
  AR.z = __builtin_amdgcn_fdot2(TH, Xl2, AR.z, false); \
  AR.z = __builtin_amdgcn_fdot2(TL, Xh2, AR.z, false); \
  AR.w = __builtin_amdgcn_fdot2(TH, Xl3, AR.w, false); \
  AR.w = __builtin_amdgcn_fdot2(TL, Xh3, AR.w, false);

// load one register pair-slot P for the tile whose window base is jlo_ / xb_
#define LOAD_P(VA, VB, P) \
    { int i2 = tid + (P) * 512; \
      int j0 = jlo_ + 2 * i2; \
      VA = make_float4(0.f, 0.f, 0.f, 0.f); VB = VA; \
      if (i2 < NPAIR) { \
          if ((unsigned)j0       < (unsigned)T_IN) VA = xb_[j0]; \
          if ((unsigned)(j0 + 1) < (unsigned)T_IN) VB = xb_[j0 + 1]; \
      } }

#define LOAD_TASK(UU) \
    { int bb_ = (UU) / NTILE; \
      int tt_ = (UU) - bb_ * NTILE; \
      const float4* __restrict__ xb_ = (const float4*)x + (size_t)bb_ * T_IN; \
      int jlo_ = (tt_ << 12) - OFFJ; \
      LOAD_P(va0, vb0, 0) LOAD_P(va1, vb1, 1) LOAD_P(va2, vb2, 2) \
      LOAD_P(va3, vb3, 3) LOAD_P(va4, vb4, 4) }

// write staged regs -> swizzled f16 channel planes (verbatim r6 stage semantics)
#define WR_P(VA, VB, P) \
    { int i2 = tid + (P) * 512; \
      if (i2 < NPAIR) { \
          int bb = SWZ(4 * i2); \
          *(h2*)(buf + bb)             = PKRTZ(VA.x, VB.x); \
          *(h2*)(buf + bb +     PLANE) = PKRTZ(VA.y, VB.y); \
          *(h2*)(buf + bb + 2 * PLANE) = PKRTZ(VA.z, VB.z); \
          *(h2*)(buf + bb + 3 * PLANE) = PKRTZ(VA.w, VB.w); } }

__launch_bounds__(512, 4)
__global__ void downsample_poly(const float* __restrict__ x,
                                const unsigned* __restrict__ ws,
                                float* __restrict__ out) {
    extern __shared__ __align__(16) char lds[];
    const int tid = threadIdx.x;
    const int dq  = tid & 63;
    const int su  = __builtin_amdgcn_readfirstlane(tid >> 6);
    const int rb0 = 128 * dq + 696 - 88 * su;

    float4 va0, va1, va2, va3, va4, vb0, vb1, vb2, vb3, vb4;

    int u = blockIdx.x;
    int parity = 0;
    LOAD_TASK(u);                                  // prologue: stage tile u into regs

    for (; u < NTASK; u += GRID, parity ^= 1) {
        char* buf = lds + parity * SLOT;

        // 1. drain regs -> f16 planes in this parity's slot
        WR_P(va0, vb0, 0) WR_P(va1, vb1, 1) WR_P(va2, vb2, 2)
        WR_P(va3, vb3, 3) WR_P(va4, vb4, 4)
        __syncthreads();

        // 2. issue next tile's HBM loads (regs free again; data used next iter)
        int un = u + GRID;
        if (un >= NTASK) un = u;                   // harmless refetch on last iter
        LOAD_TASK(un);

        // 3. compute current tile from LDS (overlaps in-flight prefetch)
        float4 a0 = make_float4(0.f,0.f,0.f,0.f), a1 = a0, a2 = a0, a3 = a0, a4 = a0;
        #pragma unroll 2
        for (int g = 0; g < 11; ++g) {
            int sw = SWZ(rb0 - 8 * g);
            h4 X0 = *(const h4*)(buf + sw);
            h4 X1 = *(const h4*)(buf + sw +     PLANE);
            h4 X2 = *(const h4*)(buf + sw + 2 * PLANE);
            h4 X3 = *(const h4*)(buf + sw + 3 * PLANE);
            h2 Xl0 = {X0[0], X0[1]}, Xh0 = {X0[2], X0[3]};
            h2 Xl1 = {X1[0], X1[1]}, Xh1 = {X1[2], X1[3]};
            h2 Xl2 = {X2[0], X2[1]}, Xh2 = {X2[2], X2[3]};
            h2 Xl3 = {X3[0], X3[1]}, Xh3 = {X3[2], X3[3]};
            const unsigned* tw = ws + (110 * su + 10 * g);   // wave-uniform
            h2 th, tl;
            th = __builtin_bit_cast(h2, tw[5]); tl = __builtin_bit_cast(h2, tw[0]); DOT_R(a0, th, tl)
            th = __builtin_bit_cast(h2, tw[6]); tl = __builtin_bit_cast(h2, tw[1]); DOT_R(a1, th, tl)
            th = __builtin_bit_cast(h2, tw[7]); tl = __builtin_bit_cast(h2, tw[2]); DOT_R(a2, th, tl)
            th = __builtin_bit_cast(h2, tw[8]); tl = __builtin_bit_cast(h2, tw[3]); DOT_R(a3, th, tl)
            th = __builtin_bit_cast(h2, tw[9]); tl = __builtin_bit_cast(h2, tw[4]); DOT_R(a4, th, tl)
        }

        // 4. reduce 8 wave-partials per (q, r) through this slot (validated r4-r6)
        __syncthreads();
        {
            float4* pp = (float4*)(buf + tid * 80);
            pp[0] = a0; pp[1] = a1; pp[2] = a2; pp[3] = a3; pp[4] = a4;
        }
        __syncthreads();
        {
            int bcu = u / NTILE;
            int q0  = (u - bcu * NTILE) << 6;
            if (tid < 320 && 5 * q0 + tid < 5 * NQ) {        // tid = qq*5 + r
                float sx = 0.f, sy = 0.f, sz = 0.f, sw2 = 0.f;
                #pragma unroll
                for (int ss = 0; ss < 8; ++ss) {
                    float4 p = *(const float4*)(buf + ss * 5120 + tid * 16);
                    sx += p.x; sy += p.y; sz += p.z; sw2 += p.w;
                }
                ((float4*)out)[(size_t)bcu * N_OUT + 5 * (size_t)q0 + tid] =
                    make_float4(sx, sy, sz, sw2);
            }
        }
    }
}

extern "C" void kernel_launch(void* const* d_in, const int* in_sizes, int n_in,
                              void* d_out, int out_size, void* d_ws, size_t ws_size,
                              hipStream_t stream) {
    const float* x = (const float*)d_in[0];
    const float* h = (const float*)d_in[1];
    float* out = (float*)d_out;
    unsigned* ws = (unsigned*)d_ws;

    // 80 KiB dynamic LDS per block (2 blocks/CU = full 160 KiB pool)
    hipFuncSetAttribute((const void*)downsample_poly,
                        hipFuncAttributeMaxDynamicSharedMemorySize, LDSSZ);

    hipLaunchKernelGGL(build_tables, dim3(1), dim3(192), 0, stream, h, ws);
    hipLaunchKernelGGL(downsample_poly, dim3(GRID), dim3(512), LDSSZ, stream,
                       x, ws, out);
}

// Round 8
// 453.554 us; speedup vs baseline: 1.0124x; 1.0124x over previous
//
#include <hip/hip_runtime.h>

// B=16, T=1280000, C=4, up=5, down=64, K=1345, n_pre_remove=11, n_out=100000
// Identity (verified r1-r7): out[b,5q+r,c] = sum_{k} tab[k][r] * x[b, 64q+192-k, c]
//   tab[k][r] = h[5k-256+64r] (0 outside [0,1345)); taps padded to 352 = 8 splits x 44
// r8: global_load_lds DMA staging (no staging VGPRs / ds_writes), raw barriers +
// counted vmcnt(8) so next tile's loads fly under current tile's fp32 compute.
// LDS = fp32 [sample][4ch] granules, XOR-swizzled: slot = m ^ ((m>>6)&7) (involution),
// applied on the DMA's per-lane GLOBAL address (lane ^ (c&7)) and on compute reads.

#define T_IN   1280000
#define N_OUT  100000
#define NQ     20000
#define KH     1345
#define NKP    352
#define NTILE  313        // tiles per batch (64 q each)
#define NTASK  5008       // NTILE * 16
#define GRID   256        // 1 block per CU
#define OFFJ   159        // jlo = 4096*t - 159 ; sample m = 64*dq + 351 - k
#define SPAN   4480       // samples per tile window (max used: 4383)
#define NCHUNK 70         // SPAN/64 DMA chunks of 1 KiB
#define BUFB   71680      // bytes per LDS buffer = SPAN*16
#define LDSSZ  143360     // two buffers

// fp32 tap tables (r4-validated layout): tab4[NKP] float4 (r=0..3), tab1[NKP] (r=4)
__global__ void build_tables(const float* __restrict__ h, float* __restrict__ ws) {
    int k = blockIdx.x * blockDim.x + threadIdx.x;
    if (k >= NKP) return;
    int m0 = 5 * k - 256;
    float4* tab4 = (float4*)ws;
    float*  tab1 = ws + NKP * 4;
    float v0 = (m0       >= 0 && m0       < KH) ? h[m0]       : 0.0f;
    float v1 = (m0 + 64  >= 0 && m0 + 64  < KH) ? h[m0 + 64]  : 0.0f;
    float v2 = (m0 + 128 >= 0 && m0 + 128 < KH) ? h[m0 + 128] : 0.0f;
    float v3 = (m0 + 192 >= 0 && m0 + 192 < KH) ? h[m0 + 192] : 0.0f;
    float v4 = (m0 + 256 >= 0 && m0 + 256 < KH) ? h[m0 + 256] : 0.0f;
    tab4[k] = make_float4(v0, v1, v2, v3);
    tab1[k] = v4;
}

// 20 fma: acc r=0..3 from T.x..w, r=4 from TB; XV = 4 channels of one sample
#define FMA20(T, TB, XV) \
  a0.x = fmaf(T.x, XV.x, a0.x); a0.y = fmaf(T.x, XV.y, a0.y); \
  a0.z = fmaf(T.x, XV.z, a0.z); a0.w = fmaf(T.x, XV.w, a0.w); \
  a1.x = fmaf(T.y, XV.x, a1.x); a1.y = fmaf(T.y, XV.y, a1.y); \
  a1.z = fmaf(T.y, XV.z, a1.z); a1.w = fmaf(T.y, XV.w, a1.w); \
  a2.x = fmaf(T.z, XV.x, a2.x); a2.y = fmaf(T.z, XV.y, a2.y); \
  a2.z = fmaf(T.z, XV.z, a2.z); a2.w = fmaf(T.z, XV.w, a2.w); \
  a3.x = fmaf(T.w, XV.x, a3.x); a3.y = fmaf(T.w, XV.y, a3.y); \
  a3.z = fmaf(T.w, XV.z, a3.z); a3.w = fmaf(T.w, XV.w, a3.w); \
  a4.x = fmaf(TB,  XV.x, a4.x); a4.y = fmaf(TB,  XV.y, a4.y); \
  a4.z = fmaf(TB,  XV.z, a4.z); a4.w = fmaf(TB,  XV.w, a4.w);

#define WAIT_VM8   asm volatile("s_waitcnt vmcnt(8)" ::: "memory")
#define WAIT_LGKM0 asm volatile("s_waitcnt lgkmcnt(0)" ::: "memory")
#define BAR() { __builtin_amdgcn_sched_barrier(0); __builtin_amdgcn_s_barrier(); \
                __builtin_amdgcn_sched_barrier(0); }

typedef const __attribute__((address_space(1))) void* gas_t;
typedef __attribute__((address_space(3))) void* las_t;

// issue DMA for task UU into LDS buffer at BUFP (wave-uniform base per chunk):
// slot i = c*64 + lane holds sample m = i ^ ((i>>6)&7) = c*64 + (lane ^ (c&7))
#define ISSUE_DMA(UU, BUFP) { \
    int bb_ = (UU) / NTILE; \
    int tt_ = (UU) - bb_ * NTILE; \
    int jlo_ = (tt_ << 12) - OFFJ; \
    const float4* __restrict__ xb_ = (const float4*)x + (size_t)bb_ * T_IN; \
    for (int c_ = wid; c_ < NCHUNK; c_ += 8) { \
        int j_ = jlo_ + (c_ << 6) + (lane ^ (c_ & 7)); \
        j_ = j_ < 0 ? 0 : (j_ >= T_IN ? T_IN - 1 : j_); \
        __builtin_amdgcn_global_load_lds((gas_t)(xb_ + j_), \
                                         (las_t)((BUFP) + (c_ << 10)), 16, 0, 0); \
    } }

__launch_bounds__(512, 2)
__global__ void downsample_poly(const float* __restrict__ x,
                                const float* __restrict__ ws,
                                float* __restrict__ out) {
    extern __shared__ __align__(16) char lds[];
    const int tid  = threadIdx.x;
    const int lane = tid & 63;
    const int wid  = __builtin_amdgcn_readfirstlane(tid >> 6);  // wave id 0..7
    const int dq   = lane;                                       // q within tile
    const int su   = wid;                                        // 44-tap split
    const float4* __restrict__ tap4 = (const float4*)ws;
    const float*  __restrict__ tap1 = ws + NKP * 4;
    const int mbase = 64 * dq + 348 - 44 * su;

    int u = blockIdx.x;
    ISSUE_DMA(u, lds)                          // prologue: tile u -> buf0

    for (int it = 0; u < NTASK; u += GRID, ++it) {
        char* bufC = lds + ((it & 1) ? BUFB : 0);   // compute from here
        char* bufN = lds + ((it & 1) ? 0 : BUFB);   // next tile lands here
        int un = u + GRID; if (un >= NTASK) un = u; // harmless dup on last iter
        ISSUE_DMA(un, bufN)

        WAIT_VM8;                               // own tile-u loads retired (in-order)
        BAR();                                  // all waves' tile-u data landed

        const int bb  = u / NTILE;
        const int tt  = u - bb * NTILE;
        const int jlo = (tt << 12) - OFFJ;
        // rare boundary patch (tiles 0 and 312 only): zero OOB-sample slots
        int lo_bad = jlo < 0 ? -jlo : 0;
        int hi_bad = T_IN - jlo; if (hi_bad > SPAN) hi_bad = SPAN;
        if (lo_bad > 0 || hi_bad < SPAN) {
            for (int m = tid; m < SPAN; m += 512)
                if (m < lo_bad || m >= hi_bad)
                    *(float4*)(bufC + ((m ^ ((m >> 6) & 7)) << 4)) =
                        make_float4(0.f, 0.f, 0.f, 0.f);
            WAIT_LGKM0; BAR();
        }

        // ---- compute: 11 groups of 4 taps; sample m+i <-> tap k0+3-i
        float4 a0 = make_float4(0.f,0.f,0.f,0.f), a1 = a0, a2 = a0, a3 = a0, a4 = a0;
        for (int g = 0; g < 11; ++g) {
            int m  = mbase - 4 * g;
            int xr = (m >> 6) & 7;               // uniform over m..m+3 (m % 64 <= 60)
            float4 X0 = *(const float4*)(bufC + (((m    ) ^ xr) << 4));
            float4 X1 = *(const float4*)(bufC + (((m + 1) ^ xr) << 4));
            float4 X2 = *(const float4*)(bufC + (((m + 2) ^ xr) << 4));
            float4 X3 = *(const float4*)(bufC + (((m + 3) ^ xr) << 4));
            int k0 = 44 * su + 4 * g;            // wave-uniform -> scalar loads
            float4 t0 = tap4[k0], t1 = tap4[k0+1], t2 = tap4[k0+2], t3 = tap4[k0+3];
            float4 u1 = *(const float4*)(tap1 + k0);
            FMA20(t3, u1.w, X0)
            FMA20(t2, u1.z, X1)
            FMA20(t1, u1.y, X2)
            FMA20(t0, u1.x, X3)
        }

        // ---- reduce 8 wave-partials per (q,r) in the now-dead compute buffer
        WAIT_LGKM0; BAR();                       // all reads of bufC complete
        {
            float4* pp = (float4*)(bufC + tid * 80);
            pp[0] = a0; pp[1] = a1; pp[2] = a2; pp[3] = a3; pp[4] = a4;
        }
        WAIT_LGKM0; BAR();
        {
            int q0 = tt << 6;
            if (tid < 320 && 5 * q0 + tid < 5 * NQ) {    // tid = qq*5 + r
                float sx = 0.f, sy = 0.f, sz = 0.f, sw = 0.f;
                #pragma unroll
                for (int ss = 0; ss < 8; ++ss) {
                    float4 p = *(const float4*)(bufC + ss * 5120 + tid * 16);
                    sx += p.x; sy += p.y; sz += p.z; sw += p.w;
                }
                ((float4*)out)[(size_t)bb * N_OUT + 5 * (size_t)q0 + tid] =
                    make_float4(sx, sy, sz, sw);
            }
        }
        WAIT_LGKM0; BAR();                       // reduce reads done before bufC reused
    }
}

extern "C" void kernel_launch(void* const* d_in, const int* in_sizes, int n_in,
                              void* d_out, int out_size, void* d_ws, size_t ws_size,
                              hipStream_t stream) {
    const float* x = (const float*)d_in[0];
    const float* h = (const float*)d_in[1];
    float* out = (float*)d_out;
    float* ws  = (float*)d_ws;

    hipFuncSetAttribute((const void*)downsample_poly,
                        hipFuncAttributeMaxDynamicSharedMemorySize, LDSSZ);

    hipLaunchKernelGGL(build_tables, dim3(2), dim3(192), 0, stream, h, ws);
    hipLaunchKernelGGL(downsample_poly, dim3(GRID), dim3(512), LDSSZ, stream,
                       x, ws, out);
}